// Round 2
// baseline (341.487 us; speedup 1.0000x reference)
//
#include <hip/hip_runtime.h>
#include <hip/hip_bf16.h>

// ---------------------------------------------------------------------------
// ZSSR involution net: conv_in(3->64,3x3,p2) -> 6x involution(K=7,G=4,gc=16)
// -> conv_out(64->12,3x3,valid) -> PixelShuffle(2).
// ALL tensors are float32 (reference is pure jnp.float32; harness passes fp32).
// ---------------------------------------------------------------------------

#define H2 130              // feature map H/W after conv_in (128+4-3+1)
#define PLANE (H2*H2)       // 16900
#define XBUF (64*PLANE)     // 1,081,600 floats per feature buffer

// ws layout (float offsets): two ping-pong feature buffers only (8.65 MB)
#define OFF_X0   0
#define OFF_X1   XBUF

// --- conv_in: 3->64, 3x3, pad=2 : (3,128,128) -> (64,130,130) --------------
__global__ __launch_bounds__(256) void conv_in_kernel(
        const float* __restrict__ inf, const float* __restrict__ W,
        const float* __restrict__ b, float* __restrict__ x0) {
    const int c = blockIdx.y;                       // wave-uniform
    int p = blockIdx.x * 256 + threadIdx.x;
    if (p >= PLANE) return;
    int h = p / H2, w = p % H2;
    float acc = b[c];
    #pragma unroll
    for (int i = 0; i < 3; ++i)
        #pragma unroll
        for (int ky = 0; ky < 3; ++ky) {
            int y = h - 2 + ky;
            if ((unsigned)y >= 128u) continue;
            #pragma unroll
            for (int kx = 0; kx < 3; ++kx) {
                int x = w - 2 + kx;
                if ((unsigned)x >= 128u) continue;
                acc += W[((c*3 + i)*3 + ky)*3 + kx] * inf[i*16384 + y*128 + x];
            }
        }
    x0[c*PLANE + p] = acc;
}

// --- involution block (fused): x(64,130,130) -> relu(inv(x)) ---------------
// 8x8 tile/WG, 256 thr = 64 px * 4 groups (group = wave -> scalar weights).
// LDS: fp32 halo tile [64][197] (row stride 14, chan stride 197) + t tile.
#define TILE 8
#define XT 14          // TILE + 6
#define CSTRIDE 197    // 14*14 + 1  (odd -> 2-way group aliasing = free)

__global__ __launch_bounds__(256) void inv_kernel(
        const float* __restrict__ xin, float* __restrict__ xout,
        const float* __restrict__ redw,   // [16][64]
        const float* __restrict__ gamma,  // [16]
        const float* __restrict__ beta,   // [16]
        const float* __restrict__ spanw,  // [196][16]
        const float* __restrict__ spanb)  // [196]
{
    __shared__ float x_lds[64 * CSTRIDE];   // 50,432 B
    __shared__ float t_lds[64 * 17];        //  4,352 B
    const int tid = threadIdx.x;
    const int h0 = blockIdx.y * TILE - 3;
    const int w0 = blockIdx.x * TILE - 3;

    // phase 1: halo load (zero-pad OOB == involution same-padding)
    if (tid < XT*XT) {
        int jy = tid / XT, jx = tid % XT;
        int gy = h0 + jy, gx = w0 + jx;
        bool ok = ((unsigned)gy < (unsigned)H2) && ((unsigned)gx < (unsigned)H2);
        const float* src = xin + gy*H2 + gx;
        #pragma unroll 8
        for (int c = 0; c < 64; ++c)
            x_lds[c*CSTRIDE + tid] = ok ? src[c*PLANE] : 0.f;
    }
    __syncthreads();

    const int g   = __builtin_amdgcn_readfirstlane(tid >> 6);  // wave-uniform group
    const int pix = tid & 63;
    const int ly  = pix >> 3, lx = pix & 7;
    const int center = (ly + 3)*XT + (lx + 3);

    // phase 2: cooperative t  (wave g computes r = 4g..4g+3 for its pixel)
    {
        float a0 = 0.f, a1 = 0.f, a2 = 0.f, a3 = 0.f;
        const float* rw = redw + g*4*64;
        for (int c = 0; c < 64; ++c) {
            float xv = x_lds[c*CSTRIDE + center];
            a0 += rw[c]      * xv;
            a1 += rw[64 + c] * xv;
            a2 += rw[128 + c]* xv;
            a3 += rw[192 + c]* xv;
        }
        int r0 = g*4;
        t_lds[pix*17 + r0 + 0] = fmaxf(gamma[r0+0]*a0 + beta[r0+0], 0.f);
        t_lds[pix*17 + r0 + 1] = fmaxf(gamma[r0+1]*a1 + beta[r0+1], 0.f);
        t_lds[pix*17 + r0 + 2] = fmaxf(gamma[r0+2]*a2 + beta[r0+2], 0.f);
        t_lds[pix*17 + r0 + 3] = fmaxf(gamma[r0+3]*a3 + beta[r0+3], 0.f);
    }
    __syncthreads();

    // phase 3: per-pixel kernel weights w[49] (span conv), scalar span_w loads
    float t16[16];
    #pragma unroll
    for (int r = 0; r < 16; ++r) t16[r] = t_lds[pix*17 + r];
    float wk[49];
    const float* sw = spanw + g*49*16;
    const float* sb = spanb + g*49;
    #pragma unroll
    for (int k = 0; k < 49; ++k) {
        float acc = sb[k];
        #pragma unroll
        for (int r = 0; r < 16; ++r) acc += sw[k*16 + r] * t16[r];
        wk[k] = acc;
    }

    // phase 4: 7x7 dynamic conv over the 16 channels of this group, + ReLU
    const int h = blockIdx.y*TILE + ly, w = blockIdx.x*TILE + lx;
    const bool valid = (h < H2) && (w < H2);
    float* dst = xout + (g*16)*PLANE + h*H2 + w;
    for (int cc = 0; cc < 16; ++cc) {
        const float* xp = &x_lds[(g*16 + cc)*CSTRIDE + ly*XT + lx];
        float acc = 0.f;
        #pragma unroll
        for (int i = 0; i < 7; ++i)
            #pragma unroll
            for (int j = 0; j < 7; ++j)
                acc += wk[i*7 + j] * xp[i*XT + j];
        if (valid) dst[cc*PLANE] = fmaxf(acc, 0.f);
    }
}

// --- conv_out (64->12, 3x3 valid) + PixelShuffle(2) ------------------------
__global__ __launch_bounds__(256) void conv_out_ps_kernel(
        const float* __restrict__ x, const float* __restrict__ W,
        const float* __restrict__ b, float* __restrict__ out) {
    int idx = blockIdx.x * 256 + threadIdx.x;       // 12*128*128 = 196608
    int o = __builtin_amdgcn_readfirstlane(idx >> 14);  // 16384 % 64 == 0 -> uniform
    int p = idx & 16383;
    int h = p >> 7, w = p & 127;
    float acc = b[o];
    const float* Wo = W + o*64*9;
    for (int c = 0; c < 64; ++c) {
        const float* xc = x + c*PLANE + h*H2 + w;
        const float* wc = Wo + c*9;
        #pragma unroll
        for (int ky = 0; ky < 3; ++ky)
            #pragma unroll
            for (int kx = 0; kx < 3; ++kx)
                acc += wc[ky*3 + kx] * xc[ky*H2 + kx];
    }
    int c3 = o >> 2, r = (o >> 1) & 1, s = o & 1;
    out[c3*65536 + (2*h + r)*256 + (2*w + s)] = acc;
}

// ---------------------------------------------------------------------------
extern "C" void kernel_launch(void* const* d_in, const int* in_sizes, int n_in,
                              void* d_out, int out_size, void* d_ws, size_t ws_size,
                              hipStream_t stream) {
    const float* inf   = (const float*)d_in[0];
    const float* cinw  = (const float*)d_in[1];
    const float* cinb  = (const float*)d_in[2];
    const float* redw  = (const float*)d_in[3];
    const float* gam   = (const float*)d_in[4];
    const float* bet   = (const float*)d_in[5];
    const float* spw   = (const float*)d_in[6];
    const float* spb   = (const float*)d_in[7];
    const float* cow   = (const float*)d_in[8];
    const float* cob   = (const float*)d_in[9];

    float* ws = (float*)d_ws;
    float* x0 = ws + OFF_X0;
    float* x1 = ws + OFF_X1;

    conv_in_kernel<<<dim3((PLANE + 255)/256, 64), 256, 0, stream>>>(
        inf, cinw, cinb, x0);

    float* cur = x0; float* nxt = x1;
    for (int l = 0; l < 6; ++l) {
        inv_kernel<<<dim3(17, 17), 256, 0, stream>>>(
            cur, nxt,
            redw + l*1024,
            gam  + l*16,
            bet  + l*16,
            spw  + l*3136,
            spb  + l*196);
        float* t = cur; cur = nxt; nxt = t;
    }

    conv_out_ps_kernel<<<196608/256, 256, 0, stream>>>(
        cur, cow, cob, (float*)d_out);
}